// Round 7
// baseline (199.923 us; speedup 1.0000x reference)
//
#include <hip/hip_runtime.h>
#include <hip/hip_bf16.h>

typedef __attribute__((ext_vector_type(8))) short short8;
typedef __attribute__((ext_vector_type(4))) float f32x4;

#define LDST 72   // bf16 elements per LDS row (144B)
#define MFMA16(a, b, c) __builtin_amdgcn_mfma_f32_16x16x32_bf16(a, b, c, 0, 0, 0)

// ---------------- R3 kernel (verified 125.7 us) ----------------
__global__ __launch_bounds__(256, 4)
void swin64_attn(const float* __restrict__ qg, const float* __restrict__ kg,
                 const float* __restrict__ vg, const float* __restrict__ tbl,
                 float* __restrict__ ox, float* __restrict__ oa) {
  __shared__ unsigned short Khi[64 * LDST], Klo[64 * LDST];
  __shared__ unsigned short Vhi[64 * LDST];      // transposed [c][j], XOR-swizzled
  __shared__ unsigned short Pb[64 * LDST];
  __shared__ float btab[128];

  const int t = threadIdx.x;
  const int b = blockIdx.x >> 7;
  const int n = blockIdx.x & 127;
  const int l = t & 63;
  const int w = t >> 6;
  const int r15 = l & 15;
  const int g4 = l >> 4;
  const int m0 = w * 16;

  const int qrow = (n * 64 + 32 + m0 + r15) & 8191;
  const float* qp = qg + ((size_t)b * 8192 + (size_t)qrow) * 64;
  const float4 qa0 = *(const float4*)(qp + g4 * 8);
  const float4 qa1 = *(const float4*)(qp + g4 * 8 + 4);
  const float4 qa2 = *(const float4*)(qp + 32 + g4 * 8);
  const float4 qa3 = *(const float4*)(qp + 32 + g4 * 8 + 4);

  if (t < 127) btab[t] = tbl[t];

#pragma unroll
  for (int s = 0; s < 2; ++s) {
    const int seg = t + s * 256;
    const int row = seg >> 3;
    const int c8 = seg & 7;
    const int p = (n * 64 + 32 + row) & 8191;
    const size_t g = ((size_t)b * 8192 + (size_t)p) * 64 + (size_t)(c8 * 8);

    {
      const float4 a0 = *(const float4*)(kg + g);
      const float4 a1 = *(const float4*)(kg + g + 4);
      const float f[8] = {a0.x, a0.y, a0.z, a0.w, a1.x, a1.y, a1.z, a1.w};
      unsigned uh[4], ul[4];
#pragma unroll
      for (int i = 0; i < 4; ++i) {
        const unsigned u0 = __float_as_uint(f[2 * i]);
        const unsigned u1 = __float_as_uint(f[2 * i + 1]);
        const float r0 = f[2 * i]     - __uint_as_float(u0 & 0xFFFF0000u);
        const float r1 = f[2 * i + 1] - __uint_as_float(u1 & 0xFFFF0000u);
        uh[i] = (u0 >> 16) | (u1 & 0xFFFF0000u);
        ul[i] = (__float_as_uint(r0) >> 16) | (__float_as_uint(r1) & 0xFFFF0000u);
      }
      *(uint4*)&Khi[row * LDST + c8 * 8] = make_uint4(uh[0], uh[1], uh[2], uh[3]);
      *(uint4*)&Klo[row * LDST + c8 * 8] = make_uint4(ul[0], ul[1], ul[2], ul[3]);
    }
    {
      const float4 a0 = *(const float4*)(vg + g);
      const float4 a1 = *(const float4*)(vg + g + 4);
      const float f[8] = {a0.x, a0.y, a0.z, a0.w, a1.x, a1.y, a1.z, a1.w};
#pragma unroll
      for (int i = 0; i < 8; ++i) {
        const int c = c8 * 8 + i;
        const int idx = c * LDST + ((((row >> 3) ^ ((c >> 3) & 7)) << 3) | (row & 7));
        Vhi[idx] = (unsigned short)((__float_as_uint(f[i]) + 0x8000u) >> 16);
      }
    }
  }

  short8 qh0, qh1, ql0, ql1;
  {
    const float f0[8] = {qa0.x, qa0.y, qa0.z, qa0.w, qa1.x, qa1.y, qa1.z, qa1.w};
    const float f1[8] = {qa2.x, qa2.y, qa2.z, qa2.w, qa3.x, qa3.y, qa3.z, qa3.w};
#pragma unroll
    for (int i = 0; i < 8; ++i) {
      const unsigned u0 = __float_as_uint(f0[i]);
      qh0[i] = (short)(u0 >> 16);
      ql0[i] = (short)(__float_as_uint(f0[i] - __uint_as_float(u0 & 0xFFFF0000u)) >> 16);
      const unsigned u1 = __float_as_uint(f1[i]);
      qh1[i] = (short)(u1 >> 16);
      ql1[i] = (short)(__float_as_uint(f1[i] - __uint_as_float(u1 & 0xFFFF0000u)) >> 16);
    }
  }
  __syncthreads();

  auto ldf = [&](const unsigned short* a, int rb, int kb) -> short8 {
    return *(const short8*)&a[(rb + r15) * LDST + kb * 32 + g4 * 8];
  };
  auto ldv = [&](const unsigned short* a, int rb, int kb) -> short8 {
    const int c = rb + r15;
    const int blk = (kb * 4 + g4) ^ ((c >> 3) & 7);
    return *(const short8*)&a[c * LDST + blk * 8];
  };

  f32x4 acc[4];
#pragma unroll
  for (int nt = 0; nt < 4; ++nt) {
    const short8 kh0 = ldf(Khi, nt * 16, 0), kh1 = ldf(Khi, nt * 16, 1);
    const short8 kl0 = ldf(Klo, nt * 16, 0), kl1 = ldf(Klo, nt * 16, 1);
    f32x4 a = {0.f, 0.f, 0.f, 0.f};
    a = MFMA16(qh0, kh0, a);
    a = MFMA16(qh1, kh1, a);
    a = MFMA16(ql0, kh0, a);
    a = MFMA16(ql1, kh1, a);
    a = MFMA16(qh0, kl0, a);
    a = MFMA16(qh1, kl1, a);
    acc[nt] = a;
  }

  float sv[4][4];
#pragma unroll
  for (int nt = 0; nt < 4; ++nt) {
#pragma unroll
    for (int r = 0; r < 4; ++r) {
      const int i = m0 + g4 * 4 + r;
      const int j = nt * 16 + r15;
      float sx = acc[nt][r] * 0.125f + btab[i - j + 63];
      if (n == 127 && ((i < 32) != (j < 32))) sx -= 100.f;
      sv[nt][r] = sx;
    }
  }

  float mx[4], rinv[4], pr[4][4];
#pragma unroll
  for (int r = 0; r < 4; ++r) {
    float m2 = fmaxf(fmaxf(sv[0][r], sv[1][r]), fmaxf(sv[2][r], sv[3][r]));
    m2 = fmaxf(m2, __shfl_xor(m2, 1));
    m2 = fmaxf(m2, __shfl_xor(m2, 2));
    m2 = fmaxf(m2, __shfl_xor(m2, 4));
    m2 = fmaxf(m2, __shfl_xor(m2, 8));
    mx[r] = m2;
  }
#pragma unroll
  for (int nt = 0; nt < 4; ++nt) {
#pragma unroll
    for (int r = 0; r < 4; ++r) pr[nt][r] = __expf(sv[nt][r] - mx[r]);
  }
#pragma unroll
  for (int r = 0; r < 4; ++r) {
    float s2 = pr[0][r] + pr[1][r] + pr[2][r] + pr[3][r];
    s2 += __shfl_xor(s2, 1);
    s2 += __shfl_xor(s2, 2);
    s2 += __shfl_xor(s2, 4);
    s2 += __shfl_xor(s2, 8);
    rinv[r] = 1.f / s2;
  }

  float* ap = oa + (size_t)blockIdx.x * 4096;
#pragma unroll
  for (int nt = 0; nt < 4; ++nt) {
#pragma unroll
    for (int r = 0; r < 4; ++r) {
      const int i = m0 + g4 * 4 + r;
      const int j = nt * 16 + r15;
      Pb[i * LDST + j] = (unsigned short)((__float_as_uint(pr[nt][r]) + 0x8000u) >> 16);
      ap[i * 64 + j] = pr[nt][r] * rinv[r];
    }
  }
  __syncthreads();

  const short8 pa0 = ldf(Pb, m0, 0), pa1 = ldf(Pb, m0, 1);
#pragma unroll
  for (int ct = 0; ct < 4; ++ct) {
    const short8 vh0 = ldv(Vhi, ct * 16, 0), vh1 = ldv(Vhi, ct * 16, 1);
    f32x4 a = {0.f, 0.f, 0.f, 0.f};
    a = MFMA16(pa0, vh0, a);
    a = MFMA16(pa1, vh1, a);
#pragma unroll
    for (int r = 0; r < 4; ++r) {
      const int i = m0 + g4 * 4 + r;
      const int p2 = (n * 64 + 32 + i) & 8191;
      ox[((size_t)b * 8192 + (size_t)p2) * 64 + ct * 16 + r15] = a[r] * rinv[r];
    }
  }
}

// ---------------- read-path probe: exact same per-block load pattern,
// no LDS / no barriers / no stores. Measures the intrinsic streaming time
// of this kernel's read traffic (rocprof reports it as a separate dispatch).
__global__ __launch_bounds__(256, 8)
void read_probe(const float* __restrict__ qg, const float* __restrict__ kg,
                const float* __restrict__ vg) {
  const int t = threadIdx.x;
  const int b = blockIdx.x >> 7;
  const int n = blockIdx.x & 127;
  const int row0 = t >> 3;
  const int c8 = t & 7;
  const size_t bbase = (size_t)b * 8192;
  const int p0 = (n * 64 + 32 + row0) & 8191;
  const int p1 = (n * 64 + 64 + row0) & 8191;
  const size_t g0 = (bbase + p0) * 64 + c8 * 8;
  const size_t g1 = (bbase + p1) * 64 + c8 * 8;

  float4 a0 = *(const float4*)(qg + g0);
  float4 a1 = *(const float4*)(qg + g0 + 4);
  float4 a2 = *(const float4*)(qg + g1);
  float4 a3 = *(const float4*)(qg + g1 + 4);
  float4 a4 = *(const float4*)(kg + g0);
  float4 a5 = *(const float4*)(kg + g0 + 4);
  float4 a6 = *(const float4*)(kg + g1);
  float4 a7 = *(const float4*)(kg + g1 + 4);
  float4 a8 = *(const float4*)(vg + g0);
  float4 a9 = *(const float4*)(vg + g0 + 4);
  float4 aa = *(const float4*)(vg + g1);
  float4 ab = *(const float4*)(vg + g1 + 4);

  float s = a0.x + a1.y + a2.z + a3.w + a4.x + a5.y + a6.z + a7.w +
            a8.x + a9.y + aa.z + ab.w;
  // keep every load live without any store (rule 17 sink)
  asm volatile("" :: "v"(s));
}

extern "C" void kernel_launch(void* const* d_in, const int* in_sizes, int n_in,
                              void* d_out, int out_size, void* d_ws, size_t ws_size,
                              hipStream_t stream) {
  const float* q = (const float*)d_in[0];
  const float* k = (const float*)d_in[1];
  const float* v = (const float*)d_in[2];
  const float* tbl = (const float*)d_in[3];
  float* ox = (float*)d_out;
  float* oa = ox + (size_t)64 * 8192 * 64;  // x first, then attn
  swin64_attn<<<dim3(8192), dim3(256), 0, stream>>>(q, k, v, tbl, ox, oa);
  read_probe<<<dim3(8192), dim3(256), 0, stream>>>(q, k, v);
}

// Round 8
// 155.505 us; speedup vs baseline: 1.2856x; 1.2856x over previous
//
#include <hip/hip_runtime.h>
#include <hip/hip_bf16.h>

typedef __attribute__((ext_vector_type(8))) short short8;
typedef __attribute__((ext_vector_type(4))) float f32x4;

#define LDST 72   // Pb row stride in bf16 elements (144B)
#define MFMA16(a, b, c) __builtin_amdgcn_mfma_f32_16x16x32_bf16(a, b, c, 0, 0, 0)

// R8: fully wave-independent kernel. No __syncthreads anywhere; no K/V LDS.
// Each of the 4 waves loads its own Q rows + the whole K window (coalesced
// float4 frags) + the whole V window (transposed scalar loads -> bf16 frags).
// Cross-wave K/V duplication is absorbed by L2 (same lines, same ~us window).
// Only LDS use: the wave-private P transpose bounce (dedicated Pb buffer,
// same-wave RAW ordered by lgkmcnt(0) + sched_barrier(0) -- rule-18 fence).
// Roll(-32) folded into global row p=(n*64+32+i)&8191 for loads and stores.
__global__ __launch_bounds__(256, 2)
void swin64_attn(const float* __restrict__ qg, const float* __restrict__ kg,
                 const float* __restrict__ vg, const float* __restrict__ tbl,
                 float* __restrict__ ox, float* __restrict__ oa) {
  __shared__ unsigned short Pb[64 * LDST];

  const int t = threadIdx.x;
  const int b = blockIdx.x >> 7;
  const int n = blockIdx.x & 127;
  const int l = t & 63;
  const int w = t >> 6;
  const int r15 = l & 15;
  const int g4 = l >> 4;
  const int m0 = w * 16;
  const size_t bbase = (size_t)b * 8192;
  const int R0 = n * 64 + 32;

  // ---- Q rows (wave-private): row m0+r15, col-octets g4*8 and 32+g4*8
  const int qrow = (R0 + m0 + r15) & 8191;
  const float* qp = qg + (bbase + qrow) * 64 + g4 * 8;
  const float4 qa0 = *(const float4*)qp;
  const float4 qa1 = *(const float4*)(qp + 4);
  const float4 qa2 = *(const float4*)(qp + 32);
  const float4 qa3 = *(const float4*)(qp + 36);

  // ---- K fragments straight from global: row nt*16+r15, cols kb*32+g4*8..+7
  float4 kfa[4][2], kfb[4][2];
#pragma unroll
  for (int nt = 0; nt < 4; ++nt) {
    const int krow = (R0 + nt * 16 + r15) & 8191;
    const float* kp = kg + (bbase + krow) * 64 + g4 * 8;
#pragma unroll
    for (int kb = 0; kb < 2; ++kb) {
      kfa[nt][kb] = *(const float4*)(kp + kb * 32);
      kfb[nt][kb] = *(const float4*)(kp + kb * 32 + 4);
    }
  }

  // ---- V fragments (transposed access, no LDS): lane holds V[j][c] for
  // j = kb*32+g4*8+i (i=0..7), c = ct*16+r15. Per instruction the wave hits
  // 4 row-clusters x 64B -- the pattern the R7 probe streamed at 5.4 TB/s.
  short8 vfr[4][2];
#pragma unroll
  for (int ct = 0; ct < 4; ++ct) {
#pragma unroll
    for (int kb = 0; kb < 2; ++kb) {
      const int c = ct * 16 + r15;
      float vt[8];
#pragma unroll
      for (int i = 0; i < 8; ++i) {
        const int p = (R0 + kb * 32 + g4 * 8 + i) & 8191;
        vt[i] = vg[(bbase + p) * 64 + c];
      }
      short8 v8;
#pragma unroll
      for (int i = 0; i < 8; ++i)
        v8[i] = (short)(unsigned short)((__float_as_uint(vt[i]) + 0x8000u) >> 16);
      vfr[ct][kb] = v8;
    }
  }

  // ---- bias direct from tbl (127 floats, L1/L2-hot): idx in [0,126]
  float bv[4][4];
#pragma unroll
  for (int nt = 0; nt < 4; ++nt)
#pragma unroll
    for (int r = 0; r < 4; ++r)
      bv[nt][r] = tbl[(m0 + g4 * 4 + r) - (nt * 16 + r15) + 63];

  // ---- Q hi/lo trunc split
  short8 qh0, qh1, ql0, ql1;
  {
    const float f0[8] = {qa0.x, qa0.y, qa0.z, qa0.w, qa1.x, qa1.y, qa1.z, qa1.w};
    const float f1[8] = {qa2.x, qa2.y, qa2.z, qa2.w, qa3.x, qa3.y, qa3.z, qa3.w};
#pragma unroll
    for (int i = 0; i < 8; ++i) {
      const unsigned u0 = __float_as_uint(f0[i]);
      qh0[i] = (short)(u0 >> 16);
      ql0[i] = (short)(__float_as_uint(f0[i] - __uint_as_float(u0 & 0xFFFF0000u)) >> 16);
      const unsigned u1 = __float_as_uint(f1[i]);
      qh1[i] = (short)(u1 >> 16);
      ql1[i] = (short)(__float_as_uint(f1[i] - __uint_as_float(u1 & 0xFFFF0000u)) >> 16);
    }
  }

  // ---- QK^T with hi/lo split (drop lo*lo)
  f32x4 acc[4];
#pragma unroll
  for (int nt = 0; nt < 4; ++nt) {
    short8 kh[2], kl[2];
#pragma unroll
    for (int kb = 0; kb < 2; ++kb) {
      const float f[8] = {kfa[nt][kb].x, kfa[nt][kb].y, kfa[nt][kb].z, kfa[nt][kb].w,
                          kfb[nt][kb].x, kfb[nt][kb].y, kfb[nt][kb].z, kfb[nt][kb].w};
      short8 h8, l8;
#pragma unroll
      for (int i = 0; i < 8; ++i) {
        const unsigned u = __float_as_uint(f[i]);
        h8[i] = (short)(u >> 16);
        l8[i] = (short)(__float_as_uint(f[i] - __uint_as_float(u & 0xFFFF0000u)) >> 16);
      }
      kh[kb] = h8;
      kl[kb] = l8;
    }
    f32x4 a = {0.f, 0.f, 0.f, 0.f};
    a = MFMA16(qh0, kh[0], a);
    a = MFMA16(qh1, kh[1], a);
    a = MFMA16(ql0, kh[0], a);
    a = MFMA16(ql1, kh[1], a);
    a = MFMA16(qh0, kl[0], a);
    a = MFMA16(qh1, kl[1], a);
    acc[nt] = a;
  }

  // ---- scale + bias + shift-mask; D layout: row = m0+g4*4+r, col = nt*16+r15
#pragma unroll
  for (int nt = 0; nt < 4; ++nt) {
#pragma unroll
    for (int r = 0; r < 4; ++r) {
      const int i = m0 + g4 * 4 + r;
      const int j = nt * 16 + r15;
      float sx = acc[nt][r] * 0.125f + bv[nt][r];
      if (n == 127 && ((i < 32) != (j < 32))) sx -= 100.f;
      acc[nt][r] = sx;
    }
  }

  // ---- row softmax across the 16-lane row group (masks 1,2,4,8)
  float mx[4], rinv[4];
#pragma unroll
  for (int r = 0; r < 4; ++r) {
    float m2 = fmaxf(fmaxf(acc[0][r], acc[1][r]), fmaxf(acc[2][r], acc[3][r]));
    m2 = fmaxf(m2, __shfl_xor(m2, 1));
    m2 = fmaxf(m2, __shfl_xor(m2, 2));
    m2 = fmaxf(m2, __shfl_xor(m2, 4));
    m2 = fmaxf(m2, __shfl_xor(m2, 8));
    mx[r] = m2;
  }
#pragma unroll
  for (int nt = 0; nt < 4; ++nt) {
#pragma unroll
    for (int r = 0; r < 4; ++r) acc[nt][r] = __expf(acc[nt][r] - mx[r]);
  }
#pragma unroll
  for (int r = 0; r < 4; ++r) {
    float s2 = acc[0][r] + acc[1][r] + acc[2][r] + acc[3][r];
    s2 += __shfl_xor(s2, 1);
    s2 += __shfl_xor(s2, 2);
    s2 += __shfl_xor(s2, 4);
    s2 += __shfl_xor(s2, 8);
    rinv[r] = 1.f / s2;
  }

  // ---- attn output (normalized f32) + P bounce into wave-private Pb rows
  float* ap = oa + (size_t)blockIdx.x * 4096;
#pragma unroll
  for (int nt = 0; nt < 4; ++nt) {
#pragma unroll
    for (int r = 0; r < 4; ++r) {
      const int i = m0 + g4 * 4 + r;
      const int j = nt * 16 + r15;
      Pb[i * LDST + j] =
          (unsigned short)((__float_as_uint(acc[nt][r]) + 0x8000u) >> 16);
      ap[i * 64 + j] = acc[nt][r] * rinv[r];
    }
  }
  // same-wave RAW fence on Pb: drain DS writes, then stop the scheduler from
  // hoisting the dependent ds_read/MFMA region above the wait (rule 18).
  asm volatile("s_waitcnt lgkmcnt(0)" ::: "memory");
  __builtin_amdgcn_sched_barrier(0);

  // ---- PV: x = P * V (bf16 frags in registers), normalize at the store
  const short8 pa0 = *(const short8*)&Pb[(m0 + r15) * LDST + g4 * 8];
  const short8 pa1 = *(const short8*)&Pb[(m0 + r15) * LDST + 32 + g4 * 8];
#pragma unroll
  for (int ct = 0; ct < 4; ++ct) {
    f32x4 a = {0.f, 0.f, 0.f, 0.f};
    a = MFMA16(pa0, vfr[ct][0], a);
    a = MFMA16(pa1, vfr[ct][1], a);
#pragma unroll
    for (int r = 0; r < 4; ++r) {
      const int i = m0 + g4 * 4 + r;
      const int p2 = (R0 + i) & 8191;
      ox[(bbase + p2) * 64 + ct * 16 + r15] = a[r] * rinv[r];
    }
  }
}

extern "C" void kernel_launch(void* const* d_in, const int* in_sizes, int n_in,
                              void* d_out, int out_size, void* d_ws, size_t ws_size,
                              hipStream_t stream) {
  const float* q = (const float*)d_in[0];
  const float* k = (const float*)d_in[1];
  const float* v = (const float*)d_in[2];
  const float* tbl = (const float*)d_in[3];
  float* ox = (float*)d_out;
  float* oa = ox + (size_t)64 * 8192 * 64;  // x first, then attn
  swin64_attn<<<dim3(8192), dim3(256), 0, stream>>>(q, k, v, tbl, ox, oa);
}